// Round 4
// baseline (1455.929 us; speedup 1.0000x reference)
//
#include <hip/hip_runtime.h>
#include <math.h>

typedef unsigned short u16;
typedef short bf16x8 __attribute__((ext_vector_type(8)));
typedef float f32x4 __attribute__((ext_vector_type(4)));

// Problem constants (B=2, S=4096, H=2048, NH=16, NKV=4, HD=128, g=1024)

__device__ __forceinline__ u16 f2bf(float x) {
  union { float f; unsigned u; } c; c.f = x;
  unsigned r = (c.u + 0x7FFFu + ((c.u >> 16) & 1u)) >> 16;  // RNE
  return (u16)r;
}
__device__ __forceinline__ float bf2f(u16 x) {
  union { unsigned u; float f; } c; c.u = ((unsigned)x) << 16;
  return c.f;
}

// async 16B global -> LDS (wave-uniform LDS base + lane*16)
#define GLD16(gp, lp)                                                   \
  __builtin_amdgcn_global_load_lds(                                     \
      (__attribute__((address_space(1))) void*)(gp),                    \
      (__attribute__((address_space(3))) void*)(lp), 16, 0, 0)

#define WAITVM(n) asm volatile("s_waitcnt vmcnt(" #n ")" ::: "memory")

// ---------------------------------------------------------------------------
// fp32 -> bf16 elementwise cast (hidden_states)
// ---------------------------------------------------------------------------
__global__ __launch_bounds__(256) void cast_bf16_vec(
    const float* __restrict__ X, u16* __restrict__ Y) {
  const size_t i = ((size_t)blockIdx.x * 256 + threadIdx.x) * 4;
  float4 v = *(const float4*)(X + i);
  ushort4 o;
  o.x = f2bf(v.x); o.y = f2bf(v.y); o.z = f2bf(v.z); o.w = f2bf(v.w);
  *(ushort4*)(Y + i) = o;
}

// ---------------------------------------------------------------------------
// W (K x N fp32, row-major) -> Wt (N x K bf16, row-major). 64x64 LDS tiles.
// ---------------------------------------------------------------------------
__global__ __launch_bounds__(256) void wt_cast(
    const float* __restrict__ W, u16* __restrict__ Wt, int K, int N) {
  const int bk = blockIdx.y * 64;
  const int bn = blockIdx.x * 64;
  __shared__ float T[64 * 65];
  const int tid = threadIdx.x;
  #pragma unroll
  for (int u = 0; u < 16; ++u) {
    int idx = tid + u * 256;
    int kl = idx >> 6, nl = idx & 63;
    T[kl * 65 + nl] = W[(size_t)(bk + kl) * N + bn + nl];
  }
  __syncthreads();
  #pragma unroll
  for (int u = 0; u < 16; ++u) {
    int idx = tid + u * 256;
    int nl = idx >> 6, kl = idx & 63;
    Wt[(size_t)(bn + nl) * K + bk + kl] = f2bf(T[kl * 65 + nl]);
  }
}

// ---------------------------------------------------------------------------
// bf16 MFMA GEMM, 256 x BN tile, ring-2 double-buffer (T1+T2+T4+T5):
//   C[M,N] = A[M,K] @ Bt[N,K]^T
// Key change vs ring-4: LDS = 2*(256+BN)*32*2B (64 KiB @BN=256, 48 @BN=128)
// -> 2 blocks/CU co-resident (4 waves/SIMD). One block's barrier/vmcnt
// stalls are filled by the other block's MFMAs (m114 mechanism) instead of
// relying on deep prefetch at 1 block/CU (which measured only 30% MfmaUtil).
// Per tile: ONE fused compute phase (32 or 16 MFMA/wave), 2 barriers.
// Staging for tile t+2 issues right after the done-reading barrier (into the
// just-freed buffer); boundary wait = counted vmcnt(L) (L loads in flight).
// Both-sides 16B-chunk XOR swizzle (verified 0 bank conflicts in r2/r3).
// 8 waves (2M x 4N); per-wave output 128 x BN/4.
// ---------------------------------------------------------------------------
template <int BN>
__global__ __launch_bounds__(512, 4) void gemm_db(
    const u16* __restrict__ A, const u16* __restrict__ Bt,
    float* __restrict__ Cf, u16* __restrict__ Cb, int M, int N, int K) {
  constexpr int NJ = BN / 64;     // B frags per wave (4 or 2)
  constexpr int LB = BN / 128;    // B loads per thread per tile (2 or 1)

  __shared__ u16 As[2][256 * 32];
  __shared__ u16 Bs[2][BN * 32];

  const int tid = threadIdx.x;

  // ---- T1: XCD swizzle (nwg % 8 == 0 for both launches: 384, 512) ----
  const int gridN = N / BN;
  const int nwg = gridDim.x * gridDim.y;
  const int orig = blockIdx.y * gridDim.x + blockIdx.x;
  const int q8 = nwg >> 3;
  const int wgid = (orig & 7) * q8 + (orig >> 3);
  const int bm = (wgid / gridN) << 8;
  const int bn = (wgid % gridN) * BN;

  const int w = tid >> 6, lane = tid & 63;
  const int col = lane & 15, quad = lane >> 4;
  const int wm = w >> 2, wn = w & 3;       // 2 x 4 wave grid
  const int sw = (col >> 1) & 3;           // read-side swizzle ((row>>1)&3)

  // ---- staging: 512 thr x 16B = 128 rows x 4 chunks per load ----
  const int srow = tid >> 2;               // 0..127
  const int scp  = tid & 3;                // dest chunk (linear for gload_lds)
  const int sc   = scp ^ ((srow >> 1) & 3);// swizzled SOURCE chunk (involution)

  const u16* aS0 = A  + (size_t)(bm + srow) * K + sc * 8;
  const u16* aS1 = A  + (size_t)(bm + srow + 128) * K + sc * 8;
  const u16* bS0 = Bt + (size_t)(bn + srow) * K + sc * 8;
  const u16* bS1 = Bt + (size_t)(bn + srow + 128) * K + sc * 8;  // BN=256 only
  const int ldst0 = srow * 32 + scp * 8;
  const int ldst1 = (srow + 128) * 32 + scp * 8;

#define STAGE(t, buf) {                                                   \
    GLD16(aS0 + (size_t)(t) * 32, &As[buf][ldst0]);                       \
    GLD16(aS1 + (size_t)(t) * 32, &As[buf][ldst1]);                       \
    GLD16(bS0 + (size_t)(t) * 32, &Bs[buf][ldst0]);                       \
    if constexpr (LB == 2) GLD16(bS1 + (size_t)(t) * 32, &Bs[buf][ldst1]); \
  }

  f32x4 acc[8][NJ];
  #pragma unroll
  for (int i = 0; i < 8; ++i)
    #pragma unroll
    for (int j = 0; j < NJ; ++j) acc[i][j] = (f32x4)(0.0f);

  const int NT = K >> 5;   // BK=32

  // ---- prologue: stage tiles 0 and 1; wait tile 0, keep tile 1 in flight
  STAGE(0, 0); STAGE(1, 1);
  if constexpr (LB == 2) WAITVM(4); else WAITVM(3);
  __builtin_amdgcn_s_barrier();
  asm volatile("" ::: "memory");

  const int aoff = (wm * 128 + col) * 32 + (quad ^ sw) * 8;
  const int boff = (wn * (BN / 4) + col) * 32 + (quad ^ sw) * 8;

  for (int t = 0; t < NT; ++t) {
    const int cur = t & 1;

    bf16x8 af[8], bfr[NJ];
    #pragma unroll
    for (int i = 0; i < 8; ++i)
      af[i] = *(const bf16x8*)&As[cur][aoff + (16 * i) * 32];
    #pragma unroll
    for (int j = 0; j < NJ; ++j)
      bfr[j] = *(const bf16x8*)&Bs[cur][boff + (16 * j) * 32];

    __builtin_amdgcn_s_setprio(1);
    #pragma unroll
    for (int i = 0; i < 8; ++i)
      #pragma unroll
      for (int j = 0; j < NJ; ++j)
        acc[i][j] = __builtin_amdgcn_mfma_f32_16x16x32_bf16(af[i], bfr[j], acc[i][j], 0, 0, 0);
    __builtin_amdgcn_s_setprio(0);

    asm volatile("" ::: "memory");
    __builtin_amdgcn_s_barrier();        // all waves done reading buf[cur]

    if (t + 2 < NT) {
      STAGE(t + 2, cur);                 // refill just-freed buffer
      if constexpr (LB == 2) WAITVM(4); else WAITVM(3);  // t+1 landed, t+2 in flight
      __builtin_amdgcn_s_barrier();
      asm volatile("" ::: "memory");
    } else if (t + 1 < NT) {
      WAITVM(0);                         // final tile's loads
      __builtin_amdgcn_s_barrier();
      asm volatile("" ::: "memory");
    }
  }

  // ---- epilogue: C/D layout col=lane&15, row=quad*4+reg [verified m89/m91]
  const int crow0 = bm + wm * 128 + quad * 4;
  const int ccol0 = bn + wn * (BN / 4) + col;
  #pragma unroll
  for (int i = 0; i < 8; ++i) {
    const int row0 = crow0 + 16 * i;
    #pragma unroll
    for (int j = 0; j < NJ; ++j) {
      const int cc = ccol0 + 16 * j;
      #pragma unroll
      for (int r = 0; r < 4; ++r) {
        if (Cb) Cb[(size_t)(row0 + r) * N + cc] = f2bf(acc[i][j][r]);
        else    Cf[(size_t)(row0 + r) * N + cc] = acc[i][j][r];
      }
    }
  }
#undef STAGE
}

// ---------------------------------------------------------------------------
// Fused RoPE on the QKV buffer (8192 rows x 3072 cols bf16).
// ---------------------------------------------------------------------------
__global__ __launch_bounds__(256) void rope_qkv(
    u16* __restrict__ QKV, const int* __restrict__ pos) {
  const unsigned idx = blockIdx.x * 256 + threadIdx.x;
  const int d = idx & 63;
  const unsigned rest = idx >> 6;
  const int hh = rest % 20;
  const unsigned bs = rest / 20;

  const int colbase = (hh < 16) ? hh * 128 : 2048 + (hh - 16) * 128;
  u16* p = QKV + (size_t)bs * 3072 + colbase + d;
  const float x0 = bf2f(p[0]);
  const float x1 = bf2f(p[64]);
  const float t = (float)pos[bs];
  const float inv_freq = __expf((float)d * -0.14391156509676332f);  // ln(1e4)/64
  float s, c;
  __sincosf(t * inv_freq, &s, &c);
  const float sc = (hh < 16) ? 0.08838834764831845f : 1.0f;  // 1/sqrt(128) into Q
  p[0]  = f2bf((x0 * c - x1 * s) * sc);
  p[64] = f2bf((x1 * c + x0 * s) * sc);
}

// ---------------------------------------------------------------------------
// V columns of QKV (offset 2560, stride 3072) -> Vt (B, NKV, 128, S)
// ---------------------------------------------------------------------------
__global__ __launch_bounds__(256) void v_transpose(
    const u16* __restrict__ QKV, u16* __restrict__ Vt) {
  const int bid = blockIdx.x;
  const int st = bid & 63;
  const int kvh = (bid >> 6) & 3;
  const int b = bid >> 8;
  __shared__ u16 T[64 * 136];
  const int tid = threadIdx.x;
  #pragma unroll
  for (int u = 0; u < 4; ++u) {
    int idx = tid + u * 256;
    int sl = idx >> 4, ch = idx & 15;
    *(uint4*)&T[sl * 136 + ch * 8] =
        *(const uint4*)(QKV + ((size_t)(b * 4096 + st * 64 + sl)) * 3072 + 2560 + kvh * 128 + ch * 8);
  }
  __syncthreads();
  #pragma unroll
  for (int u = 0; u < 32; ++u) {
    int idx = tid + u * 256;
    int d = idx >> 6, sl = idx & 63;
    Vt[((size_t)((b * 4 + kvh) * 128 + d)) * 4096 + st * 64 + sl] = T[sl * 136 + d];
  }
}

// ---------------------------------------------------------------------------
// MFMA flash attention, max-free online softmax, S2-shift indexing.
// v2: async global_load_lds staging, double-buffered K/V (unpadded, XOR-
// swizzled both-sides per rule #21), 1-deep prefetch with counted vmcnt(8),
// raw s_barrier (no implicit drain), setprio around MFMA clusters.
// ---------------------------------------------------------------------------
__global__ __launch_bounds__(256) void attn_mfma(
    const u16* __restrict__ QKV, const u16* __restrict__ Vt,
    u16* __restrict__ Ob) {
  __shared__ u16 Ks[2][64 * 128];   // [key][128d] swizzled; buf0 stages Q first
  __shared__ u16 Vs[2][128 * 64];   // [dim][64key] swizzled
  __shared__ u16 Ps[4][16 * 72];    // per-wave P [16q][64key] (padded, ds_write path)

  const int bid = blockIdx.x;
  const int qt = 15 - (bid & 15);           // heavy tiles first
  const int h  = (bid >> 4) & 15;
  const int gi = (bid >> 8) & 3;
  const int b  = bid >> 10;

  const int tid = threadIdx.x;
  const int w = tid >> 6, lane = tid & 63;
  const int col = lane & 15, quad = lane >> 4;

  const int shift = (h >= 8) ? 512 : 0;
  const int base_s = gi * 1024;
  const int kvh = h >> 2;

  // ---- staging geometry: 256 thr x 16B x 4 rounds = 16 KB tile ----
  const int kco8 = ((tid & 15) ^ ((tid >> 4) & 7)) << 3;   // u16 units
  const int vco8 = ((tid & 7) ^ ((tid >> 3) & 7)) << 3;
  const size_t krow = (size_t)(tid >> 4) * 3072 + kco8;
  const size_t vrow = (size_t)(tid >> 3) * 4096 + vco8;
  u16* kdst = &Ks[0][0] + tid * 8;   // + buf*8192 + u*2048 (lane-linear 16B)
  u16* vdst = &Vs[0][0] + tid * 8;
  const size_t vbase = (size_t)((b * 4 + kvh) * 128) * 4096;
  const u16* kgb = QKV + (size_t)b * 4096 * 3072 + 2048 + kvh * 128;

#define ASTAGE(kt_, buf_) {                                               \
    const int sk_ = (base_s + (kt_) * 64 + shift) & 4095;                 \
    const u16* ks_ = kgb + (size_t)sk_ * 3072;                            \
    const u16* vs_ = Vt + vbase + sk_;                                    \
    GLD16(ks_ + krow,             kdst + (buf_) * 8192);                  \
    GLD16(ks_ + krow + 16 * 3072, kdst + (buf_) * 8192 + 2048);           \
    GLD16(ks_ + krow + 32 * 3072, kdst + (buf_) * 8192 + 4096);           \
    GLD16(ks_ + krow + 48 * 3072, kdst + (buf_) * 8192 + 6144);           \
    GLD16(vs_ + vrow,             vdst + (buf_) * 8192);                  \
    GLD16(vs_ + vrow + 32 * 4096, vdst + (buf_) * 8192 + 2048);           \
    GLD16(vs_ + vrow + 64 * 4096, vdst + (buf_) * 8192 + 4096);           \
    GLD16(vs_ + vrow + 96 * 4096, vdst + (buf_) * 8192 + 6144);           \
  }

  // ---- stage Q tile through Ks[0] (async), grab persistent A-frags ----
  const int sq0 = (base_s + qt * 64 + shift) & 4095;
  {
    const u16* qsrc = QKV + ((size_t)(b * 4096 + sq0)) * 3072 + h * 128;
    GLD16(qsrc + krow,             kdst);
    GLD16(qsrc + krow + 16 * 3072, kdst + 2048);
    GLD16(qsrc + krow + 32 * 3072, kdst + 4096);
    GLD16(qsrc + krow + 48 * 3072, kdst + 6144);
  }
  asm volatile("s_waitcnt vmcnt(0)" ::: "memory");
  __builtin_amdgcn_s_barrier();
  asm volatile("" ::: "memory");

  const int cxor = col & 7;
  bf16x8 aq[4];  // A[m=col][k=kk*32+quad*8+j]
  {
    const int qr = w * 16 + col;   // qr&7 == col&7
    #pragma unroll
    for (int kk = 0; kk < 4; ++kk)
      aq[kk] = *(const bf16x8*)&Ks[0][qr * 128 + ((((kk << 2) + quad) ^ cxor) << 3)];
  }
  // aq must be resident before any wave's tile-0 DMA can overwrite Ks[0]
  asm volatile("s_waitcnt lgkmcnt(0)" ::: "memory");
  __builtin_amdgcn_s_barrier();
  asm volatile("" ::: "memory");

  ASTAGE(0, 0);

  f32x4 o[8];
  #pragma unroll
  for (int jd = 0; jd < 8; ++jd) o[jd] = (f32x4)(0.0f);
  float lp[4] = {0.0f, 0.0f, 0.0f, 0.0f};  // per-lane partial denominators

  u16* Pw = &Ps[w][0];
  const int qrow_l = w * 16 + quad * 4;  // + r

  for (int kt = 0; kt <= qt; ++kt) {
    const u16* Kc = &Ks[kt & 1][0];
    const u16* Vc = &Vs[kt & 1][0];
    const bool pf = (kt < qt);
    if (pf) ASTAGE(kt + 1, (kt + 1) & 1);            // fly under this tile's compute
    if (pf) asm volatile("s_waitcnt vmcnt(8)" ::: "memory");  // wait current, keep prefetch
    else    asm volatile("s_waitcnt vmcnt(0)" ::: "memory");
    __builtin_amdgcn_s_barrier();
    asm volatile("" ::: "memory");

    // ---- S = Q K^T : 16 MFMA ----
    f32x4 scv[4];
    #pragma unroll
    for (int j = 0; j < 4; ++j) scv[j] = (f32x4)(0.0f);
    __builtin_amdgcn_s_setprio(1);
    #pragma unroll
    for (int kk = 0; kk < 4; ++kk) {
      #pragma unroll
      for (int j = 0; j < 4; ++j) {
        bf16x8 bk = *(const bf16x8*)&Kc[(16 * j + col) * 128 + ((((kk << 2) + quad) ^ cxor) << 3)];
        scv[j] = __builtin_amdgcn_mfma_f32_16x16x32_bf16(aq[kk], bk, scv[j], 0, 0, 0);
      }
    }
    __builtin_amdgcn_s_setprio(0);

    // ---- exp (no max subtraction; scores bounded), mask, P write, l accum ----
    const bool last = (kt == qt);
    #pragma unroll
    for (int j = 0; j < 4; ++j) {
      #pragma unroll
      for (int r = 0; r < 4; ++r) {
        float p = __expf(scv[j][r]);
        if (last && (16 * j + col) > (qrow_l + r)) p = 0.0f;
        lp[r] += p;
        Pw[(quad * 4 + r) * 72 + 16 * j + col] = f2bf(p);
      }
    }
    // Ps is wave-private: no barrier needed (in-wave ds ordering via lgkmcnt)

    // ---- O += P V : 16 MFMA ----
    __builtin_amdgcn_s_setprio(1);
    #pragma unroll
    for (int ks = 0; ks < 2; ++ks) {
      bf16x8 ap = *(const bf16x8*)&Pw[col * 72 + ks * 32 + quad * 8];
      #pragma unroll
      for (int jd = 0; jd < 8; ++jd) {
        bf16x8 bv = *(const bf16x8*)&Vc[(16 * jd + col) * 64 + ((((ks << 2) + quad) ^ cxor) << 3)];
        o[jd] = __builtin_amdgcn_mfma_f32_16x16x32_bf16(ap, bv, o[jd], 0, 0, 0);
      }
    }
    __builtin_amdgcn_s_setprio(0);

    // all LDS reads above were consumed by MFMAs -> complete before barrier
    asm volatile("" ::: "memory");
    __builtin_amdgcn_s_barrier();
  }
#undef ASTAGE

  // ---- reduce denominators across the 16 col-lanes (same quad group) ----
  #pragma unroll
  for (int r = 0; r < 4; ++r) {
    lp[r] += __shfl_xor(lp[r], 1, 64);
    lp[r] += __shfl_xor(lp[r], 2, 64);
    lp[r] += __shfl_xor(lp[r], 4, 64);
    lp[r] += __shfl_xor(lp[r], 8, 64);
  }

  // ---- normalize + store (output lands at shifted seq pos = un-shift) ----
  #pragma unroll
  for (int r = 0; r < 4; ++r) {
    const int qg = qt * 64 + w * 16 + quad * 4 + r;
    const int sq = (base_s + qg + shift) & 4095;
    u16* dst = Ob + ((size_t)(b * 4096 + sq)) * 2048 + h * 128;
    const float inv = 1.0f / lp[r];
    #pragma unroll
    for (int jd = 0; jd < 8; ++jd)
      dst[16 * jd + col] = f2bf(o[jd][r] * inv);
  }
}

// ---------------------------------------------------------------------------
extern "C" void kernel_launch(void* const* d_in, const int* in_sizes, int n_in,
                              void* d_out, int out_size, void* d_ws, size_t ws_size,
                              hipStream_t stream) {
  const float* hs = (const float*)d_in[0];
  const int*   pos = (const int*)d_in[2];
  const float* Wq = (const float*)d_in[3];
  const float* Wk = (const float*)d_in[4];
  const float* Wv = (const float*)d_in[5];
  const float* Wo = (const float*)d_in[6];

  char* ws = (char*)d_ws;
  u16* hsb   = (u16*)ws; ws += (size_t)8192 * 2048 * 2;   // 33.5 MB
  u16* Wqkvt = (u16*)ws; ws += (size_t)3072 * 2048 * 2;   // 12.6 MB
  u16* Wot   = (u16*)ws; ws += (size_t)2048 * 2048 * 2;   //  8.4 MB
  u16* QKVb  = (u16*)ws; ws += (size_t)8192 * 3072 * 2;   // 50.3 MB
  u16* Vtt   = (u16*)ws; ws += (size_t)2 * 4 * 128 * 4096 * 2;  // 8.4 MB
  u16* Obh   = (u16*)ws; ws += (size_t)8192 * 2048 * 2;   // 33.5 MB

  dim3 blk(256);

  cast_bf16_vec<<<16384, blk, 0, stream>>>(hs, hsb);
  // Wqkvt rows: 0..2047 = Wq^T, 2048..2559 = Wk^T, 2560..3071 = Wv^T
  wt_cast<<<dim3(32, 32), blk, 0, stream>>>(Wq, Wqkvt, 2048, 2048);
  wt_cast<<<dim3(8, 32),  blk, 0, stream>>>(Wk, Wqkvt + (size_t)2048 * 2048, 2048, 512);
  wt_cast<<<dim3(8, 32),  blk, 0, stream>>>(Wv, Wqkvt + (size_t)2560 * 2048, 2048, 512);
  wt_cast<<<dim3(32, 32), blk, 0, stream>>>(Wo, Wot, 2048, 2048);

  // Fused QKV projection: (8192 x 2048) @ (3072 x 2048)^T -> 8192 x 3072 bf16
  // 256x256 tiles, ring-2 64 KiB LDS -> 2 blocks/CU; 12x32 = 384 blocks
  gemm_db<256><<<dim3(12, 32), dim3(512), 0, stream>>>(hsb, Wqkvt, nullptr, QKVb, 8192, 3072, 2048);

  // Fused RoPE (Q scaled by 1/sqrt(128)): 8192 rows x 20 heads x 64 dim-pairs
  rope_qkv<<<40960, blk, 0, stream>>>(QKVb, pos);

  v_transpose<<<512, blk, 0, stream>>>(QKVb, Vtt);

  attn_mfma<<<2048, blk, 0, stream>>>(QKVb, Vtt, Obh);

  // Out-projection: 256x128 tiles, ring-2 48 KiB -> 16x32 = 512 blocks = 2/CU
  gemm_db<128><<<dim3(16, 32), dim3(512), 0, stream>>>(Obh, Wot, (float*)d_out, nullptr, 8192, 2048, 2048);
}

// Round 5
// 496.381 us; speedup vs baseline: 2.9331x; 2.9331x over previous
//
#include <hip/hip_runtime.h>
#include <math.h>

typedef unsigned short u16;
typedef short bf16x8 __attribute__((ext_vector_type(8)));
typedef float f32x4 __attribute__((ext_vector_type(4)));

// Problem constants (B=2, S=4096, H=2048, NH=16, NKV=4, HD=128, g=1024)

__device__ __forceinline__ u16 f2bf(float x) {
  union { float f; unsigned u; } c; c.f = x;
  unsigned r = (c.u + 0x7FFFu + ((c.u >> 16) & 1u)) >> 16;  // RNE
  return (u16)r;
}
__device__ __forceinline__ float bf2f(u16 x) {
  union { unsigned u; float f; } c; c.u = ((unsigned)x) << 16;
  return c.f;
}

// async 16B global -> LDS (wave-uniform LDS base + lane*16)
#define GLD16(gp, lp)                                                   \
  __builtin_amdgcn_global_load_lds(                                     \
      (__attribute__((address_space(1))) void*)(gp),                    \
      (__attribute__((address_space(3))) void*)(lp), 16, 0, 0)

#define WAITVM(n) asm volatile("s_waitcnt vmcnt(" #n ")" ::: "memory")
#define LGKM0 { asm volatile("s_waitcnt lgkmcnt(0)" ::: "memory"); \
                __builtin_amdgcn_sched_barrier(0); }
#define BARF  { __builtin_amdgcn_s_barrier(); asm volatile("" ::: "memory"); }

// ---------------------------------------------------------------------------
// fp32 -> bf16 elementwise cast (hidden_states)
// ---------------------------------------------------------------------------
__global__ __launch_bounds__(256) void cast_bf16_vec(
    const float* __restrict__ X, u16* __restrict__ Y) {
  const size_t i = ((size_t)blockIdx.x * 256 + threadIdx.x) * 4;
  float4 v = *(const float4*)(X + i);
  ushort4 o;
  o.x = f2bf(v.x); o.y = f2bf(v.y); o.z = f2bf(v.z); o.w = f2bf(v.w);
  *(ushort4*)(Y + i) = o;
}

// ---------------------------------------------------------------------------
// W (K x N fp32, row-major) -> Wt (N x K bf16, row-major). 64x64 LDS tiles.
// ---------------------------------------------------------------------------
__global__ __launch_bounds__(256) void wt_cast(
    const float* __restrict__ W, u16* __restrict__ Wt, int K, int N) {
  const int bk = blockIdx.y * 64;
  const int bn = blockIdx.x * 64;
  __shared__ float T[64 * 65];
  const int tid = threadIdx.x;
  #pragma unroll
  for (int u = 0; u < 16; ++u) {
    int idx = tid + u * 256;
    int kl = idx >> 6, nl = idx & 63;
    T[kl * 65 + nl] = W[(size_t)(bk + kl) * N + bn + nl];
  }
  __syncthreads();
  #pragma unroll
  for (int u = 0; u < 16; ++u) {
    int idx = tid + u * 256;
    int nl = idx >> 6, kl = idx & 63;
    Wt[(size_t)(bn + nl) * K + bk + kl] = f2bf(T[kl * 65 + nl]);
  }
}

// ---------------------------------------------------------------------------
// bf16 MFMA GEMM, 256x256 tile, 4-phase/K-tile (BK=64) m201-style schedule:
//   C[M,N] = A[M,K] @ Bt[N,K]^T
// 512 thr / 8 waves. The 256x256 C-tile is computed as 4 quadrants of
// 128x128; ALL 8 waves work the SAME quadrant per phase (each wave a 64x32
// piece = 4x2 frags x 2 kslices = 16 MFMA). Each phase therefore touches
// exactly ONE A-half + ONE B-half of LDS, enabling a counted-vmcnt ledger:
//   phases: (A0,B0) (A0,B1) (A1,B1) (A1,B0)
//   stages (tile t+1, into fully-free other buffer): A0@ph0 B0@ph1 B1@ph2 A1@ph3
//   waits:  vmcnt(4) at ph0/ph1/ph3 end (covers half first-read NEXT phase+1,
//           each wait targets a stage issued 3 phases earlier); ph2 none.
//   Never vmcnt(0) in steady state; last tile peeled (vmcnt 2 / 0).
// LDS = 2 dbuf x (A 2 halves + B 2 halves) x 128x64 bf16 = 128 KiB, 1 blk/CU.
// Both-sides 16B-chunk XOR swizzle (chunk ^= row&7), verified 0 conflicts.
// Per-phase: 12 ds_read_b128 (8 A + 4 B, A reused on ph1, B1 reused on ph2),
// 2 global_load_lds_dwordx4, 1 lgkmcnt(0)+sched_barrier, 16 MFMA in
// setprio(1), 1 barrier.  VGPR ~ acc128 + frags48 + addr ~= 210 (< 256 cap;
// r4 lesson: do NOT add a min-waves launch bound - it forces spill).
// ---------------------------------------------------------------------------
__global__ __launch_bounds__(512) void gemm_8ph(
    const u16* __restrict__ A, const u16* __restrict__ Bt,
    float* __restrict__ Cf, u16* __restrict__ Cb, int M, int N, int K) {
  __shared__ u16 As[2][2][8192];   // [buf][half][128 rows x 64 cols] 64 KiB
  __shared__ u16 Bs[2][2][8192];   // 64 KiB

  const int tid = threadIdx.x;

  // ---- T1: XCD swizzle (nwg % 8 == 0: 384 / 256) ----
  const int gridN = N >> 8;
  const int nwg = gridDim.x * gridDim.y;
  const int orig = blockIdx.y * gridDim.x + blockIdx.x;
  const int wgid = (orig & 7) * (nwg >> 3) + (orig >> 3);
  const int bm = (wgid / gridN) << 8;
  const int bn = (wgid % gridN) << 8;

  const int w = tid >> 6, lane = tid & 63;
  const int col = lane & 15, quad = lane >> 4;
  const int wm = w >> 2, wn = w & 3;       // wave piece inside each quadrant

  // ---- staging: half = 128x64 bf16 = 16 KB = 512 thr x 16B x 2 rounds ----
  const int r0 = tid >> 3;                 // 0..63
  const int c0 = tid & 7;                  // dest chunk (linear for gload_lds)
  const int scc8 = ((c0 ^ (r0 & 7)) << 3); // swizzled SOURCE chunk, u16 units
                                           // ((r0+64)&7 == r0&7 -> same both rounds)
  const u16* aH00 = A  + (size_t)(bm + r0)       * K + scc8;
  const u16* aH01 = A  + (size_t)(bm + 64 + r0)  * K + scc8;
  const u16* aH10 = A  + (size_t)(bm + 128 + r0) * K + scc8;
  const u16* aH11 = A  + (size_t)(bm + 192 + r0) * K + scc8;
  const u16* bH00 = Bt + (size_t)(bn + r0)       * K + scc8;
  const u16* bH01 = Bt + (size_t)(bn + 64 + r0)  * K + scc8;
  const u16* bH10 = Bt + (size_t)(bn + 128 + r0) * K + scc8;
  const u16* bH11 = Bt + (size_t)(bn + 192 + r0) * K + scc8;

#define STG(P0, P1, DST, t_) {                                   \
    GLD16((P0) + (size_t)(t_) * 64, (DST) + tid * 8);            \
    GLD16((P1) + (size_t)(t_) * 64, (DST) + 4096 + tid * 8); }

  // ---- frag-read constants (swizzled) ----
  const int cx = col & 7;
  const int kc0 = (quad ^ cx) << 3;          // k-slice 0 chunk
  const int kc1 = ((4 + quad) ^ cx) << 3;    // k-slice 1 chunk
  const int arow = (wm * 64 + col) << 6;     // + i*1024
  const int brow = (wn * 32 + col) << 6;     // + j*1024

  bf16x8 af[4][2], bfr[2][2];
#define RDA(qa, CUR) { _Pragma("unroll") for (int i = 0; i < 4; ++i) {     \
    af[i][0] = *(const bf16x8*)&As[CUR][qa][arow + i * 1024 + kc0];        \
    af[i][1] = *(const bf16x8*)&As[CUR][qa][arow + i * 1024 + kc1]; } }
#define RDB(qb, CUR) { _Pragma("unroll") for (int j = 0; j < 2; ++j) {     \
    bfr[j][0] = *(const bf16x8*)&Bs[CUR][qb][brow + j * 1024 + kc0];       \
    bfr[j][1] = *(const bf16x8*)&Bs[CUR][qb][brow + j * 1024 + kc1]; } }
#define MMA(ACC) { _Pragma("unroll") for (int ks = 0; ks < 2; ++ks)        \
    _Pragma("unroll") for (int i = 0; i < 4; ++i)                          \
    _Pragma("unroll") for (int j = 0; j < 2; ++j)                          \
      ACC[i][j] = __builtin_amdgcn_mfma_f32_16x16x32_bf16(                 \
          af[i][ks], bfr[j][ks], ACC[i][j], 0, 0, 0); }

  f32x4 acc00[4][2], acc01[4][2], acc11[4][2], acc10[4][2];
  #pragma unroll
  for (int i = 0; i < 4; ++i)
    #pragma unroll
    for (int j = 0; j < 2; ++j) {
      acc00[i][j] = (f32x4)(0.0f); acc01[i][j] = (f32x4)(0.0f);
      acc11[i][j] = (f32x4)(0.0f); acc10[i][j] = (f32x4)(0.0f);
    }

  const int NT = K >> 6;   // BK=64

  // ---- prologue: stage tile 0 (order A0,B0,B1,A1); wait A0,B0 only ----
  STG(aH00, aH01, &As[0][0][0], 0);
  STG(bH00, bH01, &Bs[0][0][0], 0);
  STG(bH10, bH11, &Bs[0][1][0], 0);
  STG(aH10, aH11, &As[0][1][0], 0);
  WAITVM(4); BARF;

  for (int t = 0; t < NT - 1; ++t) {
    const int cur = t & 1, nxt = cur ^ 1;

    // ---- ph0: quadrant (A0,B0); stage A0[t+1] ----
    RDA(0, cur); RDB(0, cur);
    STG(aH00, aH01, &As[nxt][0][0], t + 1);
    LGKM0;
    __builtin_amdgcn_s_setprio(1); MMA(acc00); __builtin_amdgcn_s_setprio(0);
    WAITVM(4); BARF;                      // B1[t] landed (needed ph1 of... t)  [steady ledger]

    // ---- ph1: (A0,B1); stage B0[t+1] ----
    RDB(1, cur);
    STG(bH00, bH01, &Bs[nxt][0][0], t + 1);
    LGKM0;
    __builtin_amdgcn_s_setprio(1); MMA(acc01); __builtin_amdgcn_s_setprio(0);
    WAITVM(4); BARF;                      // A1[t] landed for ph2

    // ---- ph2: (A1,B1); stage B1[t+1]; no wait ----
    RDA(1, cur);
    STG(bH10, bH11, &Bs[nxt][1][0], t + 1);
    LGKM0;
    __builtin_amdgcn_s_setprio(1); MMA(acc11); __builtin_amdgcn_s_setprio(0);
    BARF;

    // ---- ph3: (A1,B0); stage A1[t+1]; boundary wait ----
    RDB(0, cur);
    STG(aH10, aH11, &As[nxt][1][0], t + 1);
    LGKM0;
    __builtin_amdgcn_s_setprio(1); MMA(acc10); __builtin_amdgcn_s_setprio(0);
    WAITVM(4); BARF;                      // A0,B0[t+1] landed for next ph0
  }

  // ---- tail tile (no stages): drain 2 -> 0 ----
  {
    const int cur = (NT - 1) & 1;
    RDA(0, cur); RDB(0, cur);
    LGKM0;
    __builtin_amdgcn_s_setprio(1); MMA(acc00); __builtin_amdgcn_s_setprio(0);
    WAITVM(2); BARF;                      // B1 landed
    RDB(1, cur);
    LGKM0;
    __builtin_amdgcn_s_setprio(1); MMA(acc01); __builtin_amdgcn_s_setprio(0);
    WAITVM(0); BARF;                      // A1 landed
    RDA(1, cur);
    LGKM0;
    __builtin_amdgcn_s_setprio(1); MMA(acc11); __builtin_amdgcn_s_setprio(0);
    RDB(0, cur);
    LGKM0;
    __builtin_amdgcn_s_setprio(1); MMA(acc10); __builtin_amdgcn_s_setprio(0);
  }

  // ---- epilogue: C/D layout col=lane&15, row=quad*4+reg [verified m89/m91]
#define WR(ACC, qa, qb) { _Pragma("unroll") for (int i = 0; i < 4; ++i)    \
    _Pragma("unroll") for (int j = 0; j < 2; ++j)                          \
    _Pragma("unroll") for (int r = 0; r < 4; ++r) {                        \
      const int rr = bm + (qa) * 128 + wm * 64 + i * 16 + quad * 4 + r;    \
      const int cc = bn + (qb) * 128 + wn * 32 + j * 16 + col;             \
      if (Cb) Cb[(size_t)rr * N + cc] = f2bf(ACC[i][j][r]);                \
      else    Cf[(size_t)rr * N + cc] = ACC[i][j][r]; } }
  WR(acc00, 0, 0); WR(acc01, 0, 1); WR(acc11, 1, 1); WR(acc10, 1, 0);
#undef WR
#undef RDA
#undef RDB
#undef MMA
#undef STG
}

// ---------------------------------------------------------------------------
// Fused RoPE on the QKV buffer (8192 rows x 3072 cols bf16).
// ---------------------------------------------------------------------------
__global__ __launch_bounds__(256) void rope_qkv(
    u16* __restrict__ QKV, const int* __restrict__ pos) {
  const unsigned idx = blockIdx.x * 256 + threadIdx.x;
  const int d = idx & 63;
  const unsigned rest = idx >> 6;
  const int hh = rest % 20;
  const unsigned bs = rest / 20;

  const int colbase = (hh < 16) ? hh * 128 : 2048 + (hh - 16) * 128;
  u16* p = QKV + (size_t)bs * 3072 + colbase + d;
  const float x0 = bf2f(p[0]);
  const float x1 = bf2f(p[64]);
  const float t = (float)pos[bs];
  const float inv_freq = __expf((float)d * -0.14391156509676332f);  // ln(1e4)/64
  float s, c;
  __sincosf(t * inv_freq, &s, &c);
  const float sc = (hh < 16) ? 0.08838834764831845f : 1.0f;  // 1/sqrt(128) into Q
  p[0]  = f2bf((x0 * c - x1 * s) * sc);
  p[64] = f2bf((x1 * c + x0 * s) * sc);
}

// ---------------------------------------------------------------------------
// V columns of QKV (offset 2560, stride 3072) -> Vt (B, NKV, 128, S)
// ---------------------------------------------------------------------------
__global__ __launch_bounds__(256) void v_transpose(
    const u16* __restrict__ QKV, u16* __restrict__ Vt) {
  const int bid = blockIdx.x;
  const int st = bid & 63;
  const int kvh = (bid >> 6) & 3;
  const int b = bid >> 8;
  __shared__ u16 T[64 * 136];
  const int tid = threadIdx.x;
  #pragma unroll
  for (int u = 0; u < 4; ++u) {
    int idx = tid + u * 256;
    int sl = idx >> 4, ch = idx & 15;
    *(uint4*)&T[sl * 136 + ch * 8] =
        *(const uint4*)(QKV + ((size_t)(b * 4096 + st * 64 + sl)) * 3072 + 2560 + kvh * 128 + ch * 8);
  }
  __syncthreads();
  #pragma unroll
  for (int u = 0; u < 32; ++u) {
    int idx = tid + u * 256;
    int d = idx >> 6, sl = idx & 63;
    Vt[((size_t)((b * 4 + kvh) * 128 + d)) * 4096 + st * 64 + sl] = T[sl * 136 + d];
  }
}

// ---------------------------------------------------------------------------
// MFMA flash attention, max-free online softmax, S2-shift indexing.
// v2 (round-2 best): async global_load_lds staging, double-buffered K/V
// (unpadded, XOR-swizzled both-sides), 1-deep prefetch with counted
// vmcnt(8), raw s_barrier, setprio around MFMA clusters.
// ---------------------------------------------------------------------------
__global__ __launch_bounds__(256) void attn_mfma(
    const u16* __restrict__ QKV, const u16* __restrict__ Vt,
    u16* __restrict__ Ob) {
  __shared__ u16 Ks[2][64 * 128];   // [key][128d] swizzled; buf0 stages Q first
  __shared__ u16 Vs[2][128 * 64];   // [dim][64key] swizzled
  __shared__ u16 Ps[4][16 * 72];    // per-wave P [16q][64key]

  const int bid = blockIdx.x;
  const int qt = 15 - (bid & 15);           // heavy tiles first
  const int h  = (bid >> 4) & 15;
  const int gi = (bid >> 8) & 3;
  const int b  = bid >> 10;

  const int tid = threadIdx.x;
  const int w = tid >> 6, lane = tid & 63;
  const int col = lane & 15, quad = lane >> 4;

  const int shift = (h >= 8) ? 512 : 0;
  const int base_s = gi * 1024;
  const int kvh = h >> 2;

  // ---- staging geometry: 256 thr x 16B x 4 rounds = 16 KB tile ----
  const int kco8 = ((tid & 15) ^ ((tid >> 4) & 7)) << 3;   // u16 units
  const int vco8 = ((tid & 7) ^ ((tid >> 3) & 7)) << 3;
  const size_t krow = (size_t)(tid >> 4) * 3072 + kco8;
  const size_t vrow = (size_t)(tid >> 3) * 4096 + vco8;
  u16* kdst = &Ks[0][0] + tid * 8;   // + buf*8192 + u*2048 (lane-linear 16B)
  u16* vdst = &Vs[0][0] + tid * 8;
  const size_t vbase = (size_t)((b * 4 + kvh) * 128) * 4096;
  const u16* kgb = QKV + (size_t)b * 4096 * 3072 + 2048 + kvh * 128;

#define ASTAGE(kt_, buf_) {                                               \
    const int sk_ = (base_s + (kt_) * 64 + shift) & 4095;                 \
    const u16* ks_ = kgb + (size_t)sk_ * 3072;                            \
    const u16* vs_ = Vt + vbase + sk_;                                    \
    GLD16(ks_ + krow,             kdst + (buf_) * 8192);                  \
    GLD16(ks_ + krow + 16 * 3072, kdst + (buf_) * 8192 + 2048);           \
    GLD16(ks_ + krow + 32 * 3072, kdst + (buf_) * 8192 + 4096);           \
    GLD16(ks_ + krow + 48 * 3072, kdst + (buf_) * 8192 + 6144);           \
    GLD16(vs_ + vrow,             vdst + (buf_) * 8192);                  \
    GLD16(vs_ + vrow + 32 * 4096, vdst + (buf_) * 8192 + 2048);           \
    GLD16(vs_ + vrow + 64 * 4096, vdst + (buf_) * 8192 + 4096);           \
    GLD16(vs_ + vrow + 96 * 4096, vdst + (buf_) * 8192 + 6144);           \
  }

  // ---- stage Q tile through Ks[0] (async), grab persistent A-frags ----
  const int sq0 = (base_s + qt * 64 + shift) & 4095;
  {
    const u16* qsrc = QKV + ((size_t)(b * 4096 + sq0)) * 3072 + h * 128;
    GLD16(qsrc + krow,             kdst);
    GLD16(qsrc + krow + 16 * 3072, kdst + 2048);
    GLD16(qsrc + krow + 32 * 3072, kdst + 4096);
    GLD16(qsrc + krow + 48 * 3072, kdst + 6144);
  }
  asm volatile("s_waitcnt vmcnt(0)" ::: "memory");
  __builtin_amdgcn_s_barrier();
  asm volatile("" ::: "memory");

  const int cxor = col & 7;
  bf16x8 aq[4];  // A[m=col][k=kk*32+quad*8+j]
  {
    const int qr = w * 16 + col;   // qr&7 == col&7
    #pragma unroll
    for (int kk = 0; kk < 4; ++kk)
      aq[kk] = *(const bf16x8*)&Ks[0][qr * 128 + ((((kk << 2) + quad) ^ cxor) << 3)];
  }
  // aq must be resident before any wave's tile-0 DMA can overwrite Ks[0]
  asm volatile("s_waitcnt lgkmcnt(0)" ::: "memory");
  __builtin_amdgcn_s_barrier();
  asm volatile("" ::: "memory");

  ASTAGE(0, 0);

  f32x4 o[8];
  #pragma unroll
  for (int jd = 0; jd < 8; ++jd) o[jd] = (f32x4)(0.0f);
  float lp[4] = {0.0f, 0.0f, 0.0f, 0.0f};  // per-lane partial denominators

  u16* Pw = &Ps[w][0];
  const int qrow_l = w * 16 + quad * 4;  // + r

  for (int kt = 0; kt <= qt; ++kt) {
    const u16* Kc = &Ks[kt & 1][0];
    const u16* Vc = &Vs[kt & 1][0];
    const bool pf = (kt < qt);
    if (pf) ASTAGE(kt + 1, (kt + 1) & 1);            // fly under this tile's compute
    if (pf) asm volatile("s_waitcnt vmcnt(8)" ::: "memory");  // wait current, keep prefetch
    else    asm volatile("s_waitcnt vmcnt(0)" ::: "memory");
    __builtin_amdgcn_s_barrier();
    asm volatile("" ::: "memory");

    // ---- S = Q K^T : 16 MFMA ----
    f32x4 scv[4];
    #pragma unroll
    for (int j = 0; j < 4; ++j) scv[j] = (f32x4)(0.0f);
    __builtin_amdgcn_s_setprio(1);
    #pragma unroll
    for (int kk = 0; kk < 4; ++kk) {
      #pragma unroll
      for (int j = 0; j < 4; ++j) {
        bf16x8 bk = *(const bf16x8*)&Kc[(16 * j + col) * 128 + ((((kk << 2) + quad) ^ cxor) << 3)];
        scv[j] = __builtin_amdgcn_mfma_f32_16x16x32_bf16(aq[kk], bk, scv[j], 0, 0, 0);
      }
    }
    __builtin_amdgcn_s_setprio(0);

    // ---- exp (no max subtraction; scores bounded), mask, P write, l accum ----
    const bool last = (kt == qt);
    #pragma unroll
    for (int j = 0; j < 4; ++j) {
      #pragma unroll
      for (int r = 0; r < 4; ++r) {
        float p = __expf(scv[j][r]);
        if (last && (16 * j + col) > (qrow_l + r)) p = 0.0f;
        lp[r] += p;
        Pw[(quad * 4 + r) * 72 + 16 * j + col] = f2bf(p);
      }
    }
    // Ps is wave-private: no barrier needed (in-wave ds ordering via lgkmcnt)

    // ---- O += P V : 16 MFMA ----
    __builtin_amdgcn_s_setprio(1);
    #pragma unroll
    for (int ks = 0; ks < 2; ++ks) {
      bf16x8 ap = *(const bf16x8*)&Pw[col * 72 + ks * 32 + quad * 8];
      #pragma unroll
      for (int jd = 0; jd < 8; ++jd) {
        bf16x8 bv = *(const bf16x8*)&Vc[(16 * jd + col) * 64 + ((((ks << 2) + quad) ^ cxor) << 3)];
        o[jd] = __builtin_amdgcn_mfma_f32_16x16x32_bf16(ap, bv, o[jd], 0, 0, 0);
      }
    }
    __builtin_amdgcn_s_setprio(0);

    // all LDS reads above were consumed by MFMAs -> complete before barrier
    asm volatile("" ::: "memory");
    __builtin_amdgcn_s_barrier();
  }
#undef ASTAGE

  // ---- reduce denominators across the 16 col-lanes (same quad group) ----
  #pragma unroll
  for (int r = 0; r < 4; ++r) {
    lp[r] += __shfl_xor(lp[r], 1, 64);
    lp[r] += __shfl_xor(lp[r], 2, 64);
    lp[r] += __shfl_xor(lp[r], 4, 64);
    lp[r] += __shfl_xor(lp[r], 8, 64);
  }

  // ---- normalize + store (output lands at shifted seq pos = un-shift) ----
  #pragma unroll
  for (int r = 0; r < 4; ++r) {
    const int qg = qt * 64 + w * 16 + quad * 4 + r;
    const int sq = (base_s + qg + shift) & 4095;
    u16* dst = Ob + ((size_t)(b * 4096 + sq)) * 2048 + h * 128;
    const float inv = 1.0f / lp[r];
    #pragma unroll
    for (int jd = 0; jd < 8; ++jd)
      dst[16 * jd + col] = f2bf(o[jd][r] * inv);
  }
}

// ---------------------------------------------------------------------------
extern "C" void kernel_launch(void* const* d_in, const int* in_sizes, int n_in,
                              void* d_out, int out_size, void* d_ws, size_t ws_size,
                              hipStream_t stream) {
  const float* hs = (const float*)d_in[0];
  const int*   pos = (const int*)d_in[2];
  const float* Wq = (const float*)d_in[3];
  const float* Wk = (const float*)d_in[4];
  const float* Wv = (const float*)d_in[5];
  const float* Wo = (const float*)d_in[6];

  char* ws = (char*)d_ws;
  u16* hsb   = (u16*)ws; ws += (size_t)8192 * 2048 * 2;   // 33.5 MB
  u16* Wqkvt = (u16*)ws; ws += (size_t)3072 * 2048 * 2;   // 12.6 MB
  u16* Wot   = (u16*)ws; ws += (size_t)2048 * 2048 * 2;   //  8.4 MB
  u16* QKVb  = (u16*)ws; ws += (size_t)8192 * 3072 * 2;   // 50.3 MB
  u16* Vtt   = (u16*)ws; ws += (size_t)2 * 4 * 128 * 4096 * 2;  // 8.4 MB
  u16* Obh   = (u16*)ws; ws += (size_t)8192 * 2048 * 2;   // 33.5 MB

  dim3 blk(256);

  cast_bf16_vec<<<16384, blk, 0, stream>>>(hs, hsb);
  // Wqkvt rows: 0..2047 = Wq^T, 2048..2559 = Wk^T, 2560..3071 = Wv^T
  wt_cast<<<dim3(32, 32), blk, 0, stream>>>(Wq, Wqkvt, 2048, 2048);
  wt_cast<<<dim3(8, 32),  blk, 0, stream>>>(Wk, Wqkvt + (size_t)2048 * 2048, 2048, 512);
  wt_cast<<<dim3(8, 32),  blk, 0, stream>>>(Wv, Wqkvt + (size_t)2560 * 2048, 2048, 512);
  wt_cast<<<dim3(32, 32), blk, 0, stream>>>(Wo, Wot, 2048, 2048);

  // Fused QKV projection: (8192 x 2048) @ (3072 x 2048)^T -> 8192 x 3072 bf16
  gemm_8ph<<<dim3(12, 32), dim3(512), 0, stream>>>(hsb, Wqkvt, nullptr, QKVb, 8192, 3072, 2048);

  // Fused RoPE (Q scaled by 1/sqrt(128)): 8192 rows x 20 heads x 64 dim-pairs
  rope_qkv<<<40960, blk, 0, stream>>>(QKVb, pos);

  v_transpose<<<512, blk, 0, stream>>>(QKVb, Vtt);

  attn_mfma<<<2048, blk, 0, stream>>>(QKVb, Vtt, Obh);

  // Out-projection: (8192 x 2048) @ (2048 x 2048)^T -> fp32 out
  gemm_8ph<<<dim3(8, 32), dim3(512), 0, stream>>>(Obh, Wot, (float*)d_out, nullptr, 8192, 2048, 2048);
}